// Round 6
// baseline (126.943 us; speedup 1.0000x reference)
//
#include <hip/hip_runtime.h>
#include <math.h>

#define NB 7
#define EPS_ 0.02f
#define ITERS1_ 120   // phase 1 (full + frozen-frame iterations)
#define ITERS2_ 80    // multiplicative phase; total 200 == reference count.
#define FULLN_  16    // first iterations forced full (transient)
#define PERIOD_ 16    // scheduled refreeze period in frozen mode
// R12/R14: trajectory matching at exactly 200 iterations is mandatory.
// R1: switch@96 FAILED. Switch stays at 120.
// R3: mant/exp phase-1 PASSED (63.1us, two DPP blocks/iter).
// R4: stale col scale + window check, PASSED absmax EXACTLY 1.525879e-05,
//     57.5us. Phase-1 ~930cy/iter vs phase-2 ~300: exponent machinery + low
//     ILP dominates, not transcendentals.
// R5: bit-op ldexp/frexp replacement REGRESSED (63.9us): ldexp/frexp are
//     full-rate on gfx950; extra VALU ops cost ~128cy/iter. Reverted.
// THIS ROUND (R6): frozen-frame phase 1. Freeze per-cell alignment constants
// RA=2^xe, CA=2^d (exact f32 powers of 2) and iterate in phase-2 shape
// (~115 instrs, no row-max/shift/frexp). Per-lane s-window [2^-24,2^24] and
// SGPR T-window [2^-50,2^50]; trigger or 16-iter schedule -> refreeze
// (renormalize + one full R4 iteration + exact col-max frame rebuild).
// Frame-equivalence (powers of 2 exact through mul/sum/rcp) => bit-identical
// to R4's trajectory while in-window; windows enforce validity.
#define TINY_ 1e-40f
#define LOG2E_ 1.4426950408889634f
#define LN2_   0.6931471805599453f

// Bare hardware transcendentals (base-2 domain).
__device__ __forceinline__ float exp2_hw(float x) {
#if __has_builtin(__builtin_amdgcn_exp2f)
    return __builtin_amdgcn_exp2f(x);
#else
    return __expf(x * LN2_);
#endif
}
__device__ __forceinline__ float log2_hw(float x) {
#if __has_builtin(__builtin_amdgcn_logf)
    return __builtin_amdgcn_logf(x);
#else
    return __logf(x) * LOG2E_;
#endif
}
__device__ __forceinline__ float rcp_hw(float x) {
#if __has_builtin(__builtin_amdgcn_rcpf)
    return __builtin_amdgcn_rcpf(x);
#else
    return 1.0f / x;
#endif
}
__device__ __forceinline__ float ldexp_hw(float x, int e) {
#if __has_builtin(__builtin_amdgcn_ldexpf)
    return __builtin_amdgcn_ldexpf(x, e);
#else
    float r; asm("v_ldexp_f32 %0, %1, %2" : "=v"(r) : "v"(x), "v"(e)); return r;
#endif
}
__device__ __forceinline__ float frexp_mant_hw(float x) {
#if __has_builtin(__builtin_amdgcn_frexp_mantf)
    return __builtin_amdgcn_frexp_mantf(x);
#else
    float r; asm("v_frexp_mant_f32 %0, %1" : "=v"(r) : "v"(x)); return r;
#endif
}
__device__ __forceinline__ int frexp_exp_hw(float x) {
#if __has_builtin(__builtin_amdgcn_frexp_expf)
    return __builtin_amdgcn_frexp_expf(x);
#else
    int r; asm("v_frexp_exp_i32_f32 %0, %1" : "=v"(r) : "v"(x)); return r;
#endif
}
// Exact bit helpers (refreeze-normalize; exact for normal v).
__device__ __forceinline__ float mant_of(float w) {   // [1,2)
    return __int_as_float((__float_as_int(w) & 0x007fffff) | 0x3f800000);
}
__device__ __forceinline__ int exp_of(float w) {
    return ((__float_as_int(w) >> 23) & 0xff) - 127;
}
// 2^e for e <= 0 (0 if e < -126): exact f32 power-of-2 constant.
__device__ __forceinline__ float exp2i_nonpos(int e) {
    return (e >= -126) ? __int_as_float((e + 127) << 23) : 0.0f;
}

// ---- DPP helpers ----
template <int CTRL>
__device__ __forceinline__ float dpp_ident(float identity, float x) {
    return __int_as_float(__builtin_amdgcn_update_dpp(
        __float_as_int(identity), __float_as_int(x), CTRL, 0xF, 0xF, false));
}
__device__ __forceinline__ float readlane63(float x) {
    return __int_as_float(__builtin_amdgcn_readlane(__float_as_int(x), 63));
}
__device__ __forceinline__ float wave_sum_bcast(float s) {
    s += dpp_ident<0x111>(0.f, s);
    s += dpp_ident<0x112>(0.f, s);
    s += dpp_ident<0x114>(0.f, s);
    s += dpp_ident<0x118>(0.f, s);
    s += dpp_ident<0x142>(0.f, s);
    s += dpp_ident<0x143>(0.f, s);
    return readlane63(s);
}

// 7-column interleaved 64-lane INT-MAX reduce -> wave-uniform SGPRs.
#define WAVE_MAXI7(v0,v1,v2,v3,v4,v5,v6, m0,m1,m2,m3,m4,m5,m6)               \
  {                                                                           \
    int r0,r1,r2,r3,r4,r5,r6;                                                 \
    asm("v_max_i32_dpp %0, %14, %14 row_shr:1 row_mask:0xf bank_mask:0xf\n\t" \
        "v_max_i32_dpp %1, %15, %15 row_shr:1 row_mask:0xf bank_mask:0xf\n\t" \
        "v_max_i32_dpp %2, %16, %16 row_shr:1 row_mask:0xf bank_mask:0xf\n\t" \
        "v_max_i32_dpp %3, %17, %17 row_shr:1 row_mask:0xf bank_mask:0xf\n\t" \
        "v_max_i32_dpp %4, %18, %18 row_shr:1 row_mask:0xf bank_mask:0xf\n\t" \
        "v_max_i32_dpp %5, %19, %19 row_shr:1 row_mask:0xf bank_mask:0xf\n\t" \
        "v_max_i32_dpp %6, %20, %20 row_shr:1 row_mask:0xf bank_mask:0xf\n\t" \
        "v_max_i32_dpp %0, %0, %0 row_shr:2 row_mask:0xf bank_mask:0xf\n\t"   \
        "v_max_i32_dpp %1, %1, %1 row_shr:2 row_mask:0xf bank_mask:0xf\n\t"   \
        "v_max_i32_dpp %2, %2, %2 row_shr:2 row_mask:0xf bank_mask:0xf\n\t"   \
        "v_max_i32_dpp %3, %3, %3 row_shr:2 row_mask:0xf bank_mask:0xf\n\t"   \
        "v_max_i32_dpp %4, %4, %4 row_shr:2 row_mask:0xf bank_mask:0xf\n\t"   \
        "v_max_i32_dpp %5, %5, %5 row_shr:2 row_mask:0xf bank_mask:0xf\n\t"   \
        "v_max_i32_dpp %6, %6, %6 row_shr:2 row_mask:0xf bank_mask:0xf\n\t"   \
        "v_max_i32_dpp %0, %0, %0 row_shr:4 row_mask:0xf bank_mask:0xf\n\t"   \
        "v_max_i32_dpp %1, %1, %1 row_shr:4 row_mask:0xf bank_mask:0xf\n\t"   \
        "v_max_i32_dpp %2, %2, %2 row_shr:4 row_mask:0xf bank_mask:0xf\n\t"   \
        "v_max_i32_dpp %3, %3, %3 row_shr:4 row_mask:0xf bank_mask:0xf\n\t"   \
        "v_max_i32_dpp %4, %4, %4 row_shr:4 row_mask:0xf bank_mask:0xf\n\t"   \
        "v_max_i32_dpp %5, %5, %5 row_shr:4 row_mask:0xf bank_mask:0xf\n\t"   \
        "v_max_i32_dpp %6, %6, %6 row_shr:4 row_mask:0xf bank_mask:0xf\n\t"   \
        "v_max_i32_dpp %0, %0, %0 row_shr:8 row_mask:0xf bank_mask:0xf\n\t"   \
        "v_max_i32_dpp %1, %1, %1 row_shr:8 row_mask:0xf bank_mask:0xf\n\t"   \
        "v_max_i32_dpp %2, %2, %2 row_shr:8 row_mask:0xf bank_mask:0xf\n\t"   \
        "v_max_i32_dpp %3, %3, %3 row_shr:8 row_mask:0xf bank_mask:0xf\n\t"   \
        "v_max_i32_dpp %4, %4, %4 row_shr:8 row_mask:0xf bank_mask:0xf\n\t"   \
        "v_max_i32_dpp %5, %5, %5 row_shr:8 row_mask:0xf bank_mask:0xf\n\t"   \
        "v_max_i32_dpp %6, %6, %6 row_shr:8 row_mask:0xf bank_mask:0xf\n\t"   \
        "v_max_i32_dpp %0, %0, %0 row_bcast:15 row_mask:0xa bank_mask:0xf\n\t"\
        "v_max_i32_dpp %1, %1, %1 row_bcast:15 row_mask:0xa bank_mask:0xf\n\t"\
        "v_max_i32_dpp %2, %2, %2 row_bcast:15 row_mask:0xa bank_mask:0xf\n\t"\
        "v_max_i32_dpp %3, %3, %3 row_bcast:15 row_mask:0xa bank_mask:0xf\n\t"\
        "v_max_i32_dpp %4, %4, %4 row_bcast:15 row_mask:0xa bank_mask:0xf\n\t"\
        "v_max_i32_dpp %5, %5, %5 row_bcast:15 row_mask:0xa bank_mask:0xf\n\t"\
        "v_max_i32_dpp %6, %6, %6 row_bcast:15 row_mask:0xa bank_mask:0xf\n\t"\
        "v_max_i32_dpp %0, %0, %0 row_bcast:31 row_mask:0xc bank_mask:0xf\n\t"\
        "v_max_i32_dpp %1, %1, %1 row_bcast:31 row_mask:0xc bank_mask:0xf\n\t"\
        "v_max_i32_dpp %2, %2, %2 row_bcast:31 row_mask:0xc bank_mask:0xf\n\t"\
        "v_max_i32_dpp %3, %3, %3 row_bcast:31 row_mask:0xc bank_mask:0xf\n\t"\
        "v_max_i32_dpp %4, %4, %4 row_bcast:31 row_mask:0xc bank_mask:0xf\n\t"\
        "v_max_i32_dpp %5, %5, %5 row_bcast:31 row_mask:0xc bank_mask:0xf\n\t"\
        "v_max_i32_dpp %6, %6, %6 row_bcast:31 row_mask:0xc bank_mask:0xf\n\t"\
        "v_readlane_b32 %7, %0, 63\n\t"                                       \
        "v_readlane_b32 %8, %1, 63\n\t"                                       \
        "v_readlane_b32 %9, %2, 63\n\t"                                       \
        "v_readlane_b32 %10, %3, 63\n\t"                                      \
        "v_readlane_b32 %11, %4, 63\n\t"                                      \
        "v_readlane_b32 %12, %5, 63\n\t"                                      \
        "v_readlane_b32 %13, %6, 63\n\t"                                      \
        "s_nop 1"                                                             \
        : "=&v"(r0), "=&v"(r1), "=&v"(r2), "=&v"(r3),                         \
          "=&v"(r4), "=&v"(r5), "=&v"(r6),                                    \
          "=s"(m0), "=s"(m1), "=s"(m2), "=s"(m3),                             \
          "=s"(m4), "=s"(m5), "=s"(m6)                                        \
        : "v"(v0), "v"(v1), "v"(v2), "v"(v3), "v"(v4), "v"(v5), "v"(v6));     \
  }

// 7-column interleaved 64-lane SUM reduce; e0..e6 clobbered; sums -> SGPRs.
#define WAVE_SUM7(e0,e1,e2,e3,e4,e5,e6, s0_,s1_,s2_,s3_,s4_,s5_,s6_)          \
    asm("s_nop 1\n\t"                                                         \
        "v_add_f32_dpp %0, %0, %0 row_shr:1 row_mask:0xf bank_mask:0xf\n\t"   \
        "v_add_f32_dpp %1, %1, %1 row_shr:1 row_mask:0xf bank_mask:0xf\n\t"   \
        "v_add_f32_dpp %2, %2, %2 row_shr:1 row_mask:0xf bank_mask:0xf\n\t"   \
        "v_add_f32_dpp %3, %3, %3 row_shr:1 row_mask:0xf bank_mask:0xf\n\t"   \
        "v_add_f32_dpp %4, %4, %4 row_shr:1 row_mask:0xf bank_mask:0xf\n\t"   \
        "v_add_f32_dpp %5, %5, %5 row_shr:1 row_mask:0xf bank_mask:0xf\n\t"   \
        "v_add_f32_dpp %6, %6, %6 row_shr:1 row_mask:0xf bank_mask:0xf\n\t"   \
        "v_add_f32_dpp %0, %0, %0 row_shr:2 row_mask:0xf bank_mask:0xf\n\t"   \
        "v_add_f32_dpp %1, %1, %1 row_shr:2 row_mask:0xf bank_mask:0xf\n\t"   \
        "v_add_f32_dpp %2, %2, %2 row_shr:2 row_mask:0xf bank_mask:0xf\n\t"   \
        "v_add_f32_dpp %3, %3, %3 row_shr:2 row_mask:0xf bank_mask:0xf\n\t"   \
        "v_add_f32_dpp %4, %4, %4 row_shr:2 row_mask:0xf bank_mask:0xf\n\t"   \
        "v_add_f32_dpp %5, %5, %5 row_shr:2 row_mask:0xf bank_mask:0xf\n\t"   \
        "v_add_f32_dpp %6, %6, %6 row_shr:2 row_mask:0xf bank_mask:0xf\n\t"   \
        "v_add_f32_dpp %0, %0, %0 row_shr:4 row_mask:0xf bank_mask:0xf\n\t"   \
        "v_add_f32_dpp %1, %1, %1 row_shr:4 row_mask:0xf bank_mask:0xf\n\t"   \
        "v_add_f32_dpp %2, %2, %2 row_shr:4 row_mask:0xf bank_mask:0xf\n\t"   \
        "v_add_f32_dpp %3, %3, %3 row_shr:4 row_mask:0xf bank_mask:0xf\n\t"   \
        "v_add_f32_dpp %4, %4, %4 row_shr:4 row_mask:0xf bank_mask:0xf\n\t"   \
        "v_add_f32_dpp %5, %5, %5 row_shr:4 row_mask:0xf bank_mask:0xf\n\t"   \
        "v_add_f32_dpp %6, %6, %6 row_shr:4 row_mask:0xf bank_mask:0xf\n\t"   \
        "v_add_f32_dpp %0, %0, %0 row_shr:8 row_mask:0xf bank_mask:0xf\n\t"   \
        "v_add_f32_dpp %1, %1, %1 row_shr:8 row_mask:0xf bank_mask:0xf\n\t"   \
        "v_add_f32_dpp %2, %2, %2 row_shr:8 row_mask:0xf bank_mask:0xf\n\t"   \
        "v_add_f32_dpp %3, %3, %3 row_shr:8 row_mask:0xf bank_mask:0xf\n\t"   \
        "v_add_f32_dpp %4, %4, %4 row_shr:8 row_mask:0xf bank_mask:0xf\n\t"   \
        "v_add_f32_dpp %5, %5, %5 row_shr:8 row_mask:0xf bank_mask:0xf\n\t"   \
        "v_add_f32_dpp %6, %6, %6 row_shr:8 row_mask:0xf bank_mask:0xf\n\t"   \
        "v_add_f32_dpp %0, %0, %0 row_bcast:15 row_mask:0xa bank_mask:0xf\n\t"\
        "v_add_f32_dpp %1, %1, %1 row_bcast:15 row_mask:0xa bank_mask:0xf\n\t"\
        "v_add_f32_dpp %2, %2, %2 row_bcast:15 row_mask:0xa bank_mask:0xf\n\t"\
        "v_add_f32_dpp %3, %3, %3 row_bcast:15 row_mask:0xa bank_mask:0xf\n\t"\
        "v_add_f32_dpp %4, %4, %4 row_bcast:15 row_mask:0xa bank_mask:0xf\n\t"\
        "v_add_f32_dpp %5, %5, %5 row_bcast:15 row_mask:0xa bank_mask:0xf\n\t"\
        "v_add_f32_dpp %6, %6, %6 row_bcast:15 row_mask:0xa bank_mask:0xf\n\t"\
        "v_add_f32_dpp %0, %0, %0 row_bcast:31 row_mask:0xc bank_mask:0xf\n\t"\
        "v_add_f32_dpp %1, %1, %1 row_bcast:31 row_mask:0xc bank_mask:0xf\n\t"\
        "v_add_f32_dpp %2, %2, %2 row_bcast:31 row_mask:0xc bank_mask:0xf\n\t"\
        "v_add_f32_dpp %3, %3, %3 row_bcast:31 row_mask:0xc bank_mask:0xf\n\t"\
        "v_add_f32_dpp %4, %4, %4 row_bcast:31 row_mask:0xc bank_mask:0xf\n\t"\
        "v_add_f32_dpp %5, %5, %5 row_bcast:31 row_mask:0xc bank_mask:0xf\n\t"\
        "v_add_f32_dpp %6, %6, %6 row_bcast:31 row_mask:0xc bank_mask:0xf\n\t"\
        "v_readlane_b32 %7, %0, 63\n\t"                                       \
        "v_readlane_b32 %8, %1, 63\n\t"                                       \
        "v_readlane_b32 %9, %2, 63\n\t"                                       \
        "v_readlane_b32 %10, %3, 63\n\t"                                      \
        "v_readlane_b32 %11, %4, 63\n\t"                                      \
        "v_readlane_b32 %12, %5, 63\n\t"                                      \
        "v_readlane_b32 %13, %6, 63\n\t"                                      \
        "s_nop 1"                                                             \
        : "+v"(e0), "+v"(e1), "+v"(e2), "+v"(e3),                             \
          "+v"(e4), "+v"(e5), "+v"(e6),                                       \
          "=s"(s0_), "=s"(s1_), "=s"(s2_), "=s"(s3_),                         \
          "=s"(s4_), "=s"(s5_), "=s"(s6_))

// Source-preserving variant (no caller copies). Bit-identical arithmetic.
#define WAVE_SUM7_SRC(w0,w1,w2,w3,w4,w5,w6, s0_,s1_,s2_,s3_,s4_,s5_,s6_)     \
  {                                                                           \
    float r0,r1,r2,r3,r4,r5,r6;                                               \
    asm("s_nop 1\n\t"                                                         \
        "v_add_f32_dpp %0, %14, %14 row_shr:1 row_mask:0xf bank_mask:0xf\n\t" \
        "v_add_f32_dpp %1, %15, %15 row_shr:1 row_mask:0xf bank_mask:0xf\n\t" \
        "v_add_f32_dpp %2, %16, %16 row_shr:1 row_mask:0xf bank_mask:0xf\n\t" \
        "v_add_f32_dpp %3, %17, %17 row_shr:1 row_mask:0xf bank_mask:0xf\n\t" \
        "v_add_f32_dpp %4, %18, %18 row_shr:1 row_mask:0xf bank_mask:0xf\n\t" \
        "v_add_f32_dpp %5, %19, %19 row_shr:1 row_mask:0xf bank_mask:0xf\n\t" \
        "v_add_f32_dpp %6, %20, %20 row_shr:1 row_mask:0xf bank_mask:0xf\n\t" \
        "v_add_f32_dpp %0, %0, %0 row_shr:2 row_mask:0xf bank_mask:0xf\n\t"   \
        "v_add_f32_dpp %1, %1, %1 row_shr:2 row_mask:0xf bank_mask:0xf\n\t"   \
        "v_add_f32_dpp %2, %2, %2 row_shr:2 row_mask:0xf bank_mask:0xf\n\t"   \
        "v_add_f32_dpp %3, %3, %3 row_shr:2 row_mask:0xf bank_mask:0xf\n\t"   \
        "v_add_f32_dpp %4, %4, %4 row_shr:2 row_mask:0xf bank_mask:0xf\n\t"   \
        "v_add_f32_dpp %5, %5, %5 row_shr:2 row_mask:0xf bank_mask:0xf\n\t"   \
        "v_add_f32_dpp %6, %6, %6 row_shr:2 row_mask:0xf bank_mask:0xf\n\t"   \
        "v_add_f32_dpp %0, %0, %0 row_shr:4 row_mask:0xf bank_mask:0xf\n\t"   \
        "v_add_f32_dpp %1, %1, %1 row_shr:4 row_mask:0xf bank_mask:0xf\n\t"   \
        "v_add_f32_dpp %2, %2, %2 row_shr:4 row_mask:0xf bank_mask:0xf\n\t"   \
        "v_add_f32_dpp %3, %3, %3 row_shr:4 row_mask:0xf bank_mask:0xf\n\t"   \
        "v_add_f32_dpp %4, %4, %4 row_shr:4 row_mask:0xf bank_mask:0xf\n\t"   \
        "v_add_f32_dpp %5, %5, %5 row_shr:4 row_mask:0xf bank_mask:0xf\n\t"   \
        "v_add_f32_dpp %6, %6, %6 row_shr:4 row_mask:0xf bank_mask:0xf\n\t"   \
        "v_add_f32_dpp %0, %0, %0 row_shr:8 row_mask:0xf bank_mask:0xf\n\t"   \
        "v_add_f32_dpp %1, %1, %1 row_shr:8 row_mask:0xf bank_mask:0xf\n\t"   \
        "v_add_f32_dpp %2, %2, %2 row_shr:8 row_mask:0xf bank_mask:0xf\n\t"   \
        "v_add_f32_dpp %3, %3, %3 row_shr:8 row_mask:0xf bank_mask:0xf\n\t"   \
        "v_add_f32_dpp %4, %4, %4 row_shr:8 row_mask:0xf bank_mask:0xf\n\t"   \
        "v_add_f32_dpp %5, %5, %5 row_shr:8 row_mask:0xf bank_mask:0xf\n\t"   \
        "v_add_f32_dpp %6, %6, %6 row_shr:8 row_mask:0xf bank_mask:0xf\n\t"   \
        "v_add_f32_dpp %0, %0, %0 row_bcast:15 row_mask:0xa bank_mask:0xf\n\t"\
        "v_add_f32_dpp %1, %1, %1 row_bcast:15 row_mask:0xa bank_mask:0xf\n\t"\
        "v_add_f32_dpp %2, %2, %2 row_bcast:15 row_mask:0xa bank_mask:0xf\n\t"\
        "v_add_f32_dpp %3, %3, %3 row_bcast:15 row_mask:0xa bank_mask:0xf\n\t"\
        "v_add_f32_dpp %4, %4, %4 row_bcast:15 row_mask:0xa bank_mask:0xf\n\t"\
        "v_add_f32_dpp %5, %5, %5 row_bcast:15 row_mask:0xa bank_mask:0xf\n\t"\
        "v_add_f32_dpp %6, %6, %6 row_bcast:15 row_mask:0xa bank_mask:0xf\n\t"\
        "v_add_f32_dpp %0, %0, %0 row_bcast:31 row_mask:0xc bank_mask:0xf\n\t"\
        "v_add_f32_dpp %1, %1, %1 row_bcast:31 row_mask:0xc bank_mask:0xf\n\t"\
        "v_add_f32_dpp %2, %2, %2 row_bcast:31 row_mask:0xc bank_mask:0xf\n\t"\
        "v_add_f32_dpp %3, %3, %3 row_bcast:31 row_mask:0xc bank_mask:0xf\n\t"\
        "v_add_f32_dpp %4, %4, %4 row_bcast:31 row_mask:0xc bank_mask:0xf\n\t"\
        "v_add_f32_dpp %5, %5, %5 row_bcast:31 row_mask:0xc bank_mask:0xf\n\t"\
        "v_add_f32_dpp %6, %6, %6 row_bcast:31 row_mask:0xc bank_mask:0xf\n\t"\
        "v_readlane_b32 %7, %0, 63\n\t"                                       \
        "v_readlane_b32 %8, %1, 63\n\t"                                       \
        "v_readlane_b32 %9, %2, 63\n\t"                                       \
        "v_readlane_b32 %10, %3, 63\n\t"                                      \
        "v_readlane_b32 %11, %4, 63\n\t"                                      \
        "v_readlane_b32 %12, %5, 63\n\t"                                      \
        "v_readlane_b32 %13, %6, 63\n\t"                                      \
        "s_nop 1"                                                             \
        : "=&v"(r0), "=&v"(r1), "=&v"(r2), "=&v"(r3),                         \
          "=&v"(r4), "=&v"(r5), "=&v"(r6),                                    \
          "=s"(s0_), "=s"(s1_), "=s"(s2_), "=s"(s3_),                         \
          "=s"(s4_), "=s"(s5_), "=s"(s6_)                                     \
        : "v"(w0), "v"(w1), "v"(w2), "v"(w3), "v"(w4), "v"(w5), "v"(w6));     \
  }

__global__ __launch_bounds__(64) void sinkhorn_kernel(
    const float* __restrict__ theta,  // [64,7]
    const float* __restrict__ phi,    // [7]
    const float* __restrict__ n,      // [64]
    const float* __restrict__ sens,   // [64]
    const float* __restrict__ err,    // [7]
    float* __restrict__ out)          // [64,7]
{
    const int lane = threadIdx.x;     // one wave: lane == row

    const float ni = n[lane];
    const float si = sens[lane];

    // Base-2 domain. K2 = (theta - C)*log2e/EPS.
    const float kscale = LOG2E_ / EPS_;
    float K2[NB];
    #pragma unroll
    for (int j = 0; j < NB; ++j)
        K2[j] = (theta[lane * NB + j] - ni * si * err[j]) * kscale;

    const float nsum   = wave_sum_bcast(ni);
    const float aT     = ni / nsum + TINY_;
    const float log_a2 = log2_hw(aT);

    // log_b2 = log2(softmax(phi) + TINY)  (uniform; per lane)
    float t2v[NB];
    #pragma unroll
    for (int j = 0; j < NB; ++j) t2v[j] = phi[j] * LOG2E_;
    float pmax = t2v[0];
    #pragma unroll
    for (int j = 1; j < NB; ++j) pmax = fmaxf(pmax, t2v[j]);
    float psum = 0.f;
    #pragma unroll
    for (int j = 0; j < NB; ++j) psum += exp2_hw(t2v[j] - pmax);
    const float lps = log2_hw(psum);
    float bT[NB], cb[NB];
    #pragma unroll
    for (int j = 0; j < NB; ++j) {
        bT[j]     = exp2_hw(t2v[j] - pmax - lps) + TINY_;
        const float log_b2 = log2_hw(bT[j]);
        cb[j]     = log_b2 - log_a2;
    }
    float b2c[NB], ibc[NB];
    #pragma unroll
    for (int j = 0; j < NB; ++j) {
        b2c[j] = exp2_hw(cb[j]);
        ibc[j] = exp2_hw(-cb[j]);
    }

    // ---- Phase 1 state: TRUE E_j = v_j * 2^Fe_j. ----
    float v[NB]; int Fe[NB];
    #pragma unroll
    for (int j = 0; j < NB; ++j) {
        const float y  = K2[j] - log_a2;
        const float yi = rintf(y);
        Fe[j] = (int)yi;
        v[j]  = exp2_hw(y - yi);              // in [2^-0.5, 2^0.5]
    }

    int XcS0 = 0, XcS1 = 0, XcS2 = 0, XcS3 = 0, XcS4 = 0, XcS5 = 0, XcS6 = 0;
    float RA[NB], CA[NB];
    bool have_frame = false;
    int since = 0;

    const unsigned LO80 = 0x17800000u, HI80 = 0x67800000u;   // [2^-80, 2^80]
    const float SLOf = __int_as_float(0x33800000);           // 2^-24
    const float SHIf = __int_as_float(0x4b800000);           // 2^+24
    const unsigned TLO = 0x26800000u, THI = 0x58800000u;     // [2^-50, 2^50]

    int it = 0;
    while (it < ITERS1_) {
        if (have_frame && it >= FULLN_ && since < PERIOD_) {
            // ---- frozen iteration (phase-2 shape + frame constants) ----
            const float f0 = v[0]*RA[0], f1 = v[1]*RA[1], f2 = v[2]*RA[2],
                        f3 = v[3]*RA[3], f4 = v[4]*RA[4], f5 = v[5]*RA[5],
                        f6 = v[6]*RA[6];
            const float s = ((f0 + f1) + (f2 + f3)) + ((f4 + f5) + f6);
            const bool ok = (s >= SLOf) && (s <= SHIf);      // NaN/inf -> false
            if (__ballot(ok) != ~0ull) { have_frame = false; continue; }
            const float rs = rcp_hw(s);
            const float g0 = (v[0]*ibc[0])*rs, g1 = (v[1]*ibc[1])*rs,
                        g2 = (v[2]*ibc[2])*rs, g3 = (v[3]*ibc[3])*rs,
                        g4 = (v[4]*ibc[4])*rs, g5 = (v[5]*ibc[5])*rs,
                        g6 = (v[6]*ibc[6])*rs;
            float h0 = g0*CA[0], h1 = g1*CA[1], h2 = g2*CA[2], h3 = g3*CA[3],
                  h4 = g4*CA[4], h5 = g5*CA[5], h6 = g6*CA[6];
            float T0, T1, T2, T3, T4, T5, T6;
            WAVE_SUM7(h0, h1, h2, h3, h4, h5, h6, T0, T1, T2, T3, T4, T5, T6);
            const unsigned u0 = __float_as_uint(T0), u1 = __float_as_uint(T1),
                           u2 = __float_as_uint(T2), u3 = __float_as_uint(T3),
                           u4 = __float_as_uint(T4), u5 = __float_as_uint(T5),
                           u6 = __float_as_uint(T6);
            const unsigned umin = min(min(min(u0, u1), min(u2, u3)),
                                      min(min(u4, u5), u6));
            const unsigned umax = max(max(max(u0, u1), max(u2, u3)),
                                      max(max(u4, u5), u6));
            if (umin < TLO || umax > THI) { have_frame = false; continue; }
            const float r0 = rcp_hw(T0), r1 = rcp_hw(T1), r2 = rcp_hw(T2),
                        r3 = rcp_hw(T3), r4 = rcp_hw(T4), r5 = rcp_hw(T5),
                        r6 = rcp_hw(T6);
            v[0] = (g0*r0)*b2c[0]; v[1] = (g1*r1)*b2c[1];
            v[2] = (g2*r2)*b2c[2]; v[3] = (g3*r3)*b2c[3];
            v[4] = (g4*r4)*b2c[4]; v[5] = (g5*r5)*b2c[5];
            v[6] = (g6*r6)*b2c[6];
            ++since; ++it; continue;
        }

        // ---- refreeze-normalize (exact for normal v) ----
        #pragma unroll
        for (int j = 0; j < NB; ++j) {
            Fe[j] += exp_of(v[j]);
            v[j]   = mant_of(v[j]);           // [1,2)
        }

        // ---- full R4 iteration on (v, Fe) ----
        {
            const int X = max(max(max(Fe[0], Fe[1]), max(Fe[2], Fe[3])),
                              max(max(Fe[4], Fe[5]), Fe[6]));
            const int xe0 = Fe[0]-X, xe1 = Fe[1]-X, xe2 = Fe[2]-X,
                      xe3 = Fe[3]-X, xe4 = Fe[4]-X, xe5 = Fe[5]-X,
                      xe6 = Fe[6]-X;
            const float f0 = ldexp_hw(v[0], xe0), f1 = ldexp_hw(v[1], xe1),
                        f2 = ldexp_hw(v[2], xe2), f3 = ldexp_hw(v[3], xe3),
                        f4 = ldexp_hw(v[4], xe4), f5 = ldexp_hw(v[5], xe5),
                        f6 = ldexp_hw(v[6], xe6);
            const float s  = ((f0 + f1) + (f2 + f3)) + ((f4 + f5) + f6);
            const float rs = rcp_hw(s);

            const float g0 = (v[0]*ibc[0])*rs, g1 = (v[1]*ibc[1])*rs,
                        g2 = (v[2]*ibc[2])*rs, g3 = (v[3]*ibc[3])*rs,
                        g4 = (v[4]*ibc[4])*rs, g5 = (v[5]*ibc[5])*rs,
                        g6 = (v[6]*ibc[6])*rs;

            int d0 = xe0-XcS0, d1 = xe1-XcS1, d2 = xe2-XcS2, d3 = xe3-XcS3,
                d4 = xe4-XcS4, d5 = xe5-XcS5, d6 = xe6-XcS6;
            float h0 = ldexp_hw(g0, d0), h1 = ldexp_hw(g1, d1),
                  h2 = ldexp_hw(g2, d2), h3 = ldexp_hw(g3, d3),
                  h4 = ldexp_hw(g4, d4), h5 = ldexp_hw(g5, d5),
                  h6 = ldexp_hw(g6, d6);

            float ss0, ss1, ss2, ss3, ss4, ss5, ss6;
            WAVE_SUM7(h0, h1, h2, h3, h4, h5, h6,
                      ss0, ss1, ss2, ss3, ss4, ss5, ss6);

            const unsigned u0 = __float_as_uint(ss0), u1 = __float_as_uint(ss1),
                           u2 = __float_as_uint(ss2), u3 = __float_as_uint(ss3),
                           u4 = __float_as_uint(ss4), u5 = __float_as_uint(ss5),
                           u6 = __float_as_uint(ss6);
            const unsigned umin = min(min(min(u0, u1), min(u2, u3)),
                                      min(min(u4, u5), u6));
            const unsigned umax = max(max(max(u0, u1), max(u2, u3)),
                                      max(max(u4, u5), u6));
            if (umin < LO80 || umax > HI80) {
                int C0, C1, C2, C3, C4, C5, C6;
                WAVE_MAXI7(xe0, xe1, xe2, xe3, xe4, xe5, xe6,
                           C0, C1, C2, C3, C4, C5, C6);
                d0 = xe0-C0; d1 = xe1-C1; d2 = xe2-C2; d3 = xe3-C3;
                d4 = xe4-C4; d5 = xe5-C5; d6 = xe6-C6;
                h0 = ldexp_hw(g0, d0); h1 = ldexp_hw(g1, d1);
                h2 = ldexp_hw(g2, d2); h3 = ldexp_hw(g3, d3);
                h4 = ldexp_hw(g4, d4); h5 = ldexp_hw(g5, d5);
                h6 = ldexp_hw(g6, d6);
                WAVE_SUM7(h0, h1, h2, h3, h4, h5, h6,
                          ss0, ss1, ss2, ss3, ss4, ss5, ss6);
                XcS0 = C0; XcS1 = C1; XcS2 = C2; XcS3 = C3;
                XcS4 = C4; XcS5 = C5; XcS6 = C6;
            }

            const float r0 = rcp_hw(ss0), r1 = rcp_hw(ss1), r2 = rcp_hw(ss2),
                        r3 = rcp_hw(ss3), r4 = rcp_hw(ss4), r5 = rcp_hw(ss5),
                        r6 = rcp_hw(ss6);
            const float w0 = (g0*r0)*b2c[0], w1 = (g1*r1)*b2c[1],
                        w2 = (g2*r2)*b2c[2], w3 = (g3*r3)*b2c[3],
                        w4 = (g4*r4)*b2c[4], w5 = (g5*r5)*b2c[5],
                        w6 = (g6*r6)*b2c[6];
            v[0] = frexp_mant_hw(w0); Fe[0] = frexp_exp_hw(w0) + d0;
            v[1] = frexp_mant_hw(w1); Fe[1] = frexp_exp_hw(w1) + d1;
            v[2] = frexp_mant_hw(w2); Fe[2] = frexp_exp_hw(w2) + d2;
            v[3] = frexp_mant_hw(w3); Fe[3] = frexp_exp_hw(w3) + d3;
            v[4] = frexp_mant_hw(w4); Fe[4] = frexp_exp_hw(w4) + d4;
            v[5] = frexp_mant_hw(w5); Fe[5] = frexp_exp_hw(w5) + d5;
            v[6] = frexp_mant_hw(w6); Fe[6] = frexp_exp_hw(w6) + d6;
        }

        // ---- frame build (for upcoming frozen iterations) ----
        if (it + 1 >= FULLN_ && it + 1 < ITERS1_) {
            const int X2 = max(max(max(Fe[0], Fe[1]), max(Fe[2], Fe[3])),
                               max(max(Fe[4], Fe[5]), Fe[6]));
            const int y0 = Fe[0]-X2, y1 = Fe[1]-X2, y2 = Fe[2]-X2,
                      y3 = Fe[3]-X2, y4 = Fe[4]-X2, y5 = Fe[5]-X2,
                      y6 = Fe[6]-X2;
            WAVE_MAXI7(y0, y1, y2, y3, y4, y5, y6,
                       XcS0, XcS1, XcS2, XcS3, XcS4, XcS5, XcS6);
            RA[0] = exp2i_nonpos(y0); CA[0] = exp2i_nonpos(y0 - XcS0);
            RA[1] = exp2i_nonpos(y1); CA[1] = exp2i_nonpos(y1 - XcS1);
            RA[2] = exp2i_nonpos(y2); CA[2] = exp2i_nonpos(y2 - XcS2);
            RA[3] = exp2i_nonpos(y3); CA[3] = exp2i_nonpos(y3 - XcS3);
            RA[4] = exp2i_nonpos(y4); CA[4] = exp2i_nonpos(y4 - XcS4);
            RA[5] = exp2i_nonpos(y5); CA[5] = exp2i_nonpos(y5 - XcS5);
            RA[6] = exp2i_nonpos(y6); CA[6] = exp2i_nonpos(y6 - XcS6);
            have_frame = true;
        }
        since = 0; ++it;
    }

    // ---- Switch: U = E * 2^-cb = ldexp(v*ib, Fe); underflow -> 0. ----
    float U[NB], B[NB];
    #pragma unroll
    for (int j = 0; j < NB; ++j) {
        U[j] = ldexp_hw(v[j] * ibc[j], Fe[j]);
        B[j] = b2c[j];
    }

    // ---- Phase 2: multiplicative, 80 iterations (verbatim). ----
    for (int it2 = 0; it2 < ITERS2_; ++it2) {
        float p0 = U[0] * B[0], p1 = U[1] * B[1], p2 = U[2] * B[2],
              p3 = U[3] * B[3], p4 = U[4] * B[4], p5 = U[5] * B[5],
              p6 = U[6] * B[6];
        const float s = ((p0 + p1) + (p2 + p3)) + ((p4 + p5) + p6);
        const float rs = rcp_hw(s);
        float w0 = U[0] * rs, w1 = U[1] * rs, w2 = U[2] * rs,
              w3 = U[3] * rs, w4 = U[4] * rs, w5 = U[5] * rs,
              w6 = U[6] * rs;

        float ss0, ss1, ss2, ss3, ss4, ss5, ss6;
        WAVE_SUM7_SRC(w0, w1, w2, w3, w4, w5, w6,
                      ss0, ss1, ss2, ss3, ss4, ss5, ss6);

        const float r0 = rcp_hw(ss0);
        const float r1 = rcp_hw(ss1);
        const float r2 = rcp_hw(ss2);
        const float r3 = rcp_hw(ss3);
        const float r4 = rcp_hw(ss4);
        const float r5 = rcp_hw(ss5);
        const float r6 = rcp_hw(ss6);
        U[0] = w0 * r0; U[1] = w1 * r1; U[2] = w2 * r2; U[3] = w3 * r3;
        U[4] = w4 * r4; U[5] = w5 * r5; U[6] = w6 * r6;
    }

    // ---- Epilogue: P = U * bT; normalize by total (+TINY) ----
    float pr[NB];
    float rowsum = 0.f;
    #pragma unroll
    for (int j = 0; j < NB; ++j) {
        pr[j] = U[j] * bT[j];
        rowsum += pr[j];
    }
    const float total = wave_sum_bcast(rowsum);   // ~1 at convergence
    const float inv = 1.0f / (total + TINY_);
    #pragma unroll
    for (int j = 0; j < NB; ++j)
        out[lane * NB + j] = pr[j] * inv;
}

extern "C" void kernel_launch(void* const* d_in, const int* in_sizes, int n_in,
                              void* d_out, int out_size, void* d_ws, size_t ws_size,
                              hipStream_t stream) {
    const float* theta = (const float*)d_in[0];
    const float* phi   = (const float*)d_in[1];
    const float* n     = (const float*)d_in[2];
    const float* sens  = (const float*)d_in[3];
    const float* err   = (const float*)d_in[4];
    float* out = (float*)d_out;

    sinkhorn_kernel<<<1, 64, 0, stream>>>(theta, phi, n, sens, err, out);
}

// Round 7
// 111.303 us; speedup vs baseline: 1.1405x; 1.1405x over previous
//
#include <hip/hip_runtime.h>
#include <math.h>

#define NB 7
#define EPS_ 0.02f
#define ITERS1_ 120   // log-domain phase (R2-equivalent logic, transposed)
#define ITERS2_ 80    // multiplicative phase; total 200 == reference count.
// R12/R14: trajectory matching at exactly 200 iterations is mandatory.
// R1: switch@96 FAILED (rescues fire in (96,120]). Switch stays at 120.
// R3-R6: single-wave representation tricks (mant/exp, stale scale, bit ops,
// frozen frames) all land 57-73us: the 1-wave serial spine (49-op DPP block +
// dependency chain, zero TLP) is irreducible. THIS ROUND (R7): transpose to
// 7 waves / 448 threads, thread(lane=row, wave=col) owns one cell.
// Column reduce: per-wave 6-DPP+readlane (7 instrs, parallel across SIMDs).
// Row reduce: LDS round, stride-9 (2-way bank = free), R2 sum order.
// Row window+ballot / col window+rescue mirror R2 exactly (f32-quality
// trajectory; R3/R5 showed such perturbations land ~1e-5..5e-5 << 1.04e-3).
// 1 barrier/iter via parity double-buffer.
#define TINY_ 1e-40f
#define LOG2E_ 1.4426950408889634f
#define LN2_   0.6931471805599453f

__device__ __forceinline__ float exp2_hw(float x) {
#if __has_builtin(__builtin_amdgcn_exp2f)
    return __builtin_amdgcn_exp2f(x);
#else
    return __expf(x * LN2_);
#endif
}
__device__ __forceinline__ float log2_hw(float x) {
#if __has_builtin(__builtin_amdgcn_logf)
    return __builtin_amdgcn_logf(x);
#else
    return __logf(x) * LOG2E_;
#endif
}
__device__ __forceinline__ float rcp_hw(float x) {
#if __has_builtin(__builtin_amdgcn_rcpf)
    return __builtin_amdgcn_rcpf(x);
#else
    return 1.0f / x;
#endif
}

// ---- DPP helpers (proven in prior rounds) ----
template <int CTRL>
__device__ __forceinline__ float dpp_ident(float identity, float x) {
    return __int_as_float(__builtin_amdgcn_update_dpp(
        __float_as_int(identity), __float_as_int(x), CTRL, 0xF, 0xF, false));
}
__device__ __forceinline__ float readlane63(float x) {
    return __int_as_float(__builtin_amdgcn_readlane(__float_as_int(x), 63));
}
__device__ __forceinline__ float wave_sum_bcast(float s) {
    s += dpp_ident<0x111>(0.f, s);
    s += dpp_ident<0x112>(0.f, s);
    s += dpp_ident<0x114>(0.f, s);
    s += dpp_ident<0x118>(0.f, s);
    s += dpp_ident<0x142>(0.f, s);
    s += dpp_ident<0x143>(0.f, s);
    return readlane63(s);
}
__device__ __forceinline__ float wave_max_bcast(float m) {
    const float NI = __int_as_float(0xff800000);
    m = fmaxf(m, dpp_ident<0x111>(NI, m));
    m = fmaxf(m, dpp_ident<0x112>(NI, m));
    m = fmaxf(m, dpp_ident<0x114>(NI, m));
    m = fmaxf(m, dpp_ident<0x118>(NI, m));
    m = fmaxf(m, dpp_ident<0x142>(NI, m));
    m = fmaxf(m, dpp_ident<0x143>(NI, m));
    return readlane63(m);
}

#define STRIDE_ 9   // 9 coprime 32 -> 2 lanes/bank on row reads/writes (free)

__global__ __launch_bounds__(448) void sinkhorn_kernel(
    const float* __restrict__ theta,  // [64,7]
    const float* __restrict__ phi,    // [7]
    const float* __restrict__ n,      // [64]
    const float* __restrict__ sens,   // [64]
    const float* __restrict__ err,    // [7]
    float* __restrict__ out)          // [64,7]
{
    const int tid  = threadIdx.x;
    const int lane = tid & 63;        // row
    const int wid  = tid >> 6;        // column 0..6 (one wave per column)

    __shared__ float bufEA[2][64 * STRIDE_ + 8];   // exp2(a) per cell
    __shared__ float bufAA[2][64 * STRIDE_ + 8];   // a per cell (rescue)
    __shared__ float ldsS[8];                      // epilogue column sums

    const float ni = n[lane];
    const float si = sens[lane];
    const float ej = err[wid];
    const float th = theta[lane * NB + wid];

    // nsum identical in every wave (same per-lane ni, same tree).
    const float nsum   = wave_sum_bcast(ni);
    const float aT     = ni / nsum + TINY_;
    const float log_a2 = log2_hw(aT);

    // softmax(phi): same scalar sequence as R2 (sequential psum order).
    float t2v0 = phi[0] * LOG2E_, t2v1 = phi[1] * LOG2E_,
          t2v2 = phi[2] * LOG2E_, t2v3 = phi[3] * LOG2E_,
          t2v4 = phi[4] * LOG2E_, t2v5 = phi[5] * LOG2E_,
          t2v6 = phi[6] * LOG2E_;
    float pmax = t2v0;
    pmax = fmaxf(pmax, t2v1); pmax = fmaxf(pmax, t2v2);
    pmax = fmaxf(pmax, t2v3); pmax = fmaxf(pmax, t2v4);
    pmax = fmaxf(pmax, t2v5); pmax = fmaxf(pmax, t2v6);
    float psum = exp2_hw(t2v0 - pmax);
    psum += exp2_hw(t2v1 - pmax); psum += exp2_hw(t2v2 - pmax);
    psum += exp2_hw(t2v3 - pmax); psum += exp2_hw(t2v4 - pmax);
    psum += exp2_hw(t2v5 - pmax); psum += exp2_hw(t2v6 - pmax);
    const float lps  = log2_hw(psum);
    const float myt2 = phi[wid] * LOG2E_;
    const float bTj  = exp2_hw(myt2 - pmax - lps) + TINY_;
    const float lb2j = log2_hw(bTj);
    const float cbj  = lb2j - log_a2;

    const float kscale = LOG2E_ / EPS_;
    float t = (th - ni * si * ej) * kscale - lb2j;

    const float LOF = __int_as_float(0x0D800000);  // 2^-100
    const float HIF = __int_as_float(0x71800000);  // 2^+100
    const int   base = lane * STRIDE_ + wid;
    const int   rb   = lane * STRIDE_;

    // ---- Phase 1: log-domain, transposed. 1 barrier/iter (parity dbuf). ----
    for (int it = 0; it < ITERS1_; ++it) {
        const int p = it & 1;
        const float a = t + cbj;
        bufEA[p][base] = exp2_hw(a);
        bufAA[p][base] = a;
        __syncthreads();

        const float e0 = bufEA[p][rb + 0], e1 = bufEA[p][rb + 1],
                    e2 = bufEA[p][rb + 2], e3 = bufEA[p][rb + 3],
                    e4 = bufEA[p][rb + 4], e5 = bufEA[p][rb + 5],
                    e6 = bufEA[p][rb + 6];
        const float s = ((e0 + e1) + (e2 + e3)) + ((e4 + e5) + e6);
        float L;
        const bool ok = (s >= LOF) && (s <= HIF);   // NaN/inf -> false
        if (__ballot(ok) == ~0ull) {                // identical in all waves
            L = log2_hw(s);
        } else {
            const float a0 = bufAA[p][rb + 0], a1 = bufAA[p][rb + 1],
                        a2 = bufAA[p][rb + 2], a3 = bufAA[p][rb + 3],
                        a4 = bufAA[p][rb + 4], a5 = bufAA[p][rb + 5],
                        a6 = bufAA[p][rb + 6];
            const float m = fmaxf(fmaxf(fmaxf(a0, a1), fmaxf(a2, a3)),
                                  fmaxf(fmaxf(a4, a5), a6));
            const float s2 = ((exp2_hw(a0 - m) + exp2_hw(a1 - m))
                            + (exp2_hw(a2 - m) + exp2_hw(a3 - m)))
                           + ((exp2_hw(a4 - m) + exp2_hw(a5 - m))
                            + exp2_hw(a6 - m));
            L = m + log2_hw(s2);
        }

        const float q = t - L;
        const float e = exp2_hw(q);
        const float ss = wave_sum_bcast(e);         // wave-uniform
        if (ss >= LOF && ss <= HIF) {               // wave-local decision
            t = q - log2_hw(ss);
        } else {
            const float M   = wave_max_bcast(q);
            const float e2  = exp2_hw(q - M);
            const float ss2 = wave_sum_bcast(e2);   // in [1,64]
            t = q - (M + log2_hw(ss2));
        }
    }

    // ---- Switch @120 (R13-validated mechanics): U = 2^t, underflow->0. ----
    float U = exp2_hw(t);
    const float Bj = exp2_hw(cbj);

    // ---- Phase 2: multiplicative, transposed. 1 barrier/iter. ----
    for (int it2 = 0; it2 < ITERS2_; ++it2) {
        const int p = it2 & 1;
        bufEA[p][base] = U * Bj;
        __syncthreads();
        const float p0 = bufEA[p][rb + 0], p1 = bufEA[p][rb + 1],
                    p2 = bufEA[p][rb + 2], p3 = bufEA[p][rb + 3],
                    p4 = bufEA[p][rb + 4], p5 = bufEA[p][rb + 5],
                    p6 = bufEA[p][rb + 6];
        const float s  = ((p0 + p1) + (p2 + p3)) + ((p4 + p5) + p6);
        const float rs = rcp_hw(s);
        const float w  = U * rs;
        const float ss = wave_sum_bcast(w);
        U = w * rcp_hw(ss);
    }

    // ---- Epilogue: P = U*bT; normalize by total (+TINY). ----
    const float pr = U * bTj;
    const float cs = wave_sum_bcast(pr);   // column sum (wave-uniform)
    if (lane == 0) ldsS[wid] = cs;
    __syncthreads();
    const float total = ((ldsS[0] + ldsS[1]) + (ldsS[2] + ldsS[3]))
                      + ((ldsS[4] + ldsS[5]) + ldsS[6]);
    out[lane * NB + wid] = pr * (1.0f / (total + TINY_));
}

extern "C" void kernel_launch(void* const* d_in, const int* in_sizes, int n_in,
                              void* d_out, int out_size, void* d_ws, size_t ws_size,
                              hipStream_t stream) {
    const float* theta = (const float*)d_in[0];
    const float* phi   = (const float*)d_in[1];
    const float* n     = (const float*)d_in[2];
    const float* sens  = (const float*)d_in[3];
    const float* err   = (const float*)d_in[4];
    float* out = (float*)d_out;

    sinkhorn_kernel<<<1, 448, 0, stream>>>(theta, phi, n, sens, err, out);
}